// Round 10
// baseline (5721.844 us; speedup 1.0000x reference)
//
#include <hip/hip_runtime.h>

#define B_ 64
#define S_ 256
#define F_ 256
#define H_ 1024

typedef __attribute__((ext_vector_type(8))) short bf16x8;
typedef __attribute__((ext_vector_type(4))) float f32x4;
typedef unsigned long long u64;

#define MFMA(a, b, c) __builtin_amdgcn_mfma_f32_16x16x32_bf16(a, b, c, 0, 0, 0)
#define CBAR() asm volatile("" ::: "memory")

__device__ __forceinline__ float sig(float v) { return 1.0f / (1.0f + __expf(-v)); }
__device__ __forceinline__ float tanh_(float v) { return 1.0f - 2.0f / (__expf(2.0f * v) + 1.0f); }
__device__ __forceinline__ short bfr(float f) {  // fp32 -> bf16 RNE
    unsigned u = __float_as_uint(f);
    u += 0x7fffu + ((u >> 16) & 1u);
    return (short)(u >> 16);
}

// agent-scope write-through 4B store (visible at coherence point)
__device__ __forceinline__ void st4(short* base, size_t byteoff, unsigned v) {
    __hip_atomic_store((unsigned*)((char*)base + byteoff), v,
                       __ATOMIC_RELAXED, __HIP_MEMORY_SCOPE_AGENT);
}

// agent-scope 16B fragment load as 2x8B atomic loads (coherence point; no fences needed)
__device__ __forceinline__ bf16x8 lda16(const short* p) {
    union { u64 q[2]; bf16x8 v; } r;
    r.q[0] = __hip_atomic_load((const u64*)p,       __ATOMIC_RELAXED, __HIP_MEMORY_SCOPE_AGENT);
    r.q[1] = __hip_atomic_load((const u64*)(p + 4), __ATOMIC_RELAXED, __HIP_MEMORY_SCOPE_AGENT);
    return r.v;
}

__device__ __forceinline__ void flag_add(unsigned* line) {
    asm volatile("s_waitcnt vmcnt(0)" ::: "memory");
    __hip_atomic_fetch_add(line, 1u, __ATOMIC_RELAXED, __HIP_MEMORY_SCOPE_AGENT);
}

// global wait on 32-line counter set (wave 0 only): lane i polls line i&31, butterfly-sum
__device__ __forceinline__ void flag_wait_g(unsigned* lines, int lane31, unsigned tgt) {
    for (;;) {
        unsigned s = __hip_atomic_load(&lines[lane31 * 16], __ATOMIC_RELAXED,
                                       __HIP_MEMORY_SCOPE_AGENT);
        s += __shfl_xor(s, 1);
        s += __shfl_xor(s, 2);
        s += __shfl_xor(s, 4);
        s += __shfl_xor(s, 8);
        s += __shfl_xor(s, 16);
        if (s >= tgt) break;
        __builtin_amdgcn_s_sleep(1);
    }
    CBAR();
}

__device__ __forceinline__ void tok_spin(volatile unsigned* tk, unsigned v) {
    while (*tk < v) __builtin_amdgcn_s_sleep(1);
    CBAR();
}

// x pre-conversion into A-frag layout: [t][kf 8][m 4][lane 64][8]
__global__ __launch_bounds__(256) void conv_x(const float* __restrict__ x,
                                              short* __restrict__ xbf) {
    int tid = blockIdx.x * 256 + threadIdx.x;
    int lane = tid & 63;
    int m = (tid >> 6) & 3;
    int kf = (tid >> 8) & 7;
    int t = tid >> 11;
    int b = m * 16 + (lane & 15);
    int kb = kf * 32 + (lane >> 4) * 8;
    const float* src = x + ((size_t)b * S_ + t) * F_ + kb;
    float4 v0 = *(const float4*)src, v1 = *(const float4*)(src + 4);
    bf16x8 o;
    o[0] = bfr(v0.x); o[1] = bfr(v0.y); o[2] = bfr(v0.z); o[3] = bfr(v0.w);
    o[4] = bfr(v1.x); o[5] = bfr(v1.y); o[6] = bfr(v1.z); o[7] = bfr(v1.w);
    *(bf16x8*)(xbf + (size_t)tid * 8) = o;
}

__global__ void zero_f(float* __restrict__ p, int n) {
    int i = blockIdx.x * blockDim.x + threadIdx.x;
    if (i < n) p[i] = 0.0f;
}

// ---- one-time: M = Wa * fcW  ([4096,256]x[256,1024]) into B-frag layout; c0 = Wa * fcb ----
// grid 256 (one per nf), block 256.
__global__ __launch_bounds__(256) void precomp(const float* __restrict__ Wih0,
                                               const float* __restrict__ fcW,
                                               const float* __restrict__ fcb,
                                               short* __restrict__ Mf,
                                               float* __restrict__ c0ws) {
    __shared__ float WaL[16][256];   // 16 KB
    const int nf = blockIdx.x, tid = threadIdx.x;
    #pragma unroll
    for (int r = 0; r < 16; ++r) {
        int rowp = nf * 16 + r;
        int up = rowp >> 2, gat = rowp & 3;
        WaL[r][tid] = Wih0[(size_t)(gat * H_ + up) * 512 + 256 + tid];
    }
    __syncthreads();
    f32x4 acc[16];
    #pragma unroll
    for (int r = 0; r < 16; ++r) acc[r] = (f32x4){0, 0, 0, 0};
    for (int c = 0; c < 256; ++c) {
        f32x4 wv = *(const f32x4*)&fcW[(size_t)c * 1024 + tid * 4];
        #pragma unroll
        for (int r = 0; r < 16; ++r) acc[r] += WaL[r][c] * wv;
    }
    #pragma unroll
    for (int r = 0; r < 16; ++r) {
        #pragma unroll
        for (int jj = 0; jj < 4; ++jj) {
            int h = tid * 4 + jj;
            int kf = h >> 5;
            int lane = r + ((h >> 3) & 3) * 16;
            int j = h & 7;
            Mf[((size_t)nf * 32 + kf) * 512 + lane * 8 + j] = bfr(acc[r][jj]);
        }
    }
    if (tid < 16) {
        float s = 0.0f;
        for (int c = 0; c < 256; ++c) s += WaL[tid][c] * fcb[c];
        c0ws[nf * 16 + tid] = s;
    }
}

// gate un-interleave: after 3 shfl_xor every lane holds i,f,g,o for its (b,u).
#define GATES(v)                                                        \
    float x1 = __shfl_xor((v), 1), x2 = __shfl_xor((v), 2), x3 = __shfl_xor((v), 3); \
    float aL = g1 ? x1 : (v), aH = g1 ? x3 : x2;                        \
    float bL = g1 ? (v) : x1, bH = g1 ? x2 : x3;                        \
    float i_ = g2 ? aH : aL;                                            \
    float f_ = g2 ? bH : bL;                                            \
    float gc = g2 ? aL : aH;                                            \
    float o_ = g2 ? bL : bH;                                            \
    i_ = sig(i_); f_ = sig(f_); o_ = sig(o_); gc = tanh_(gc);

__global__ __launch_bounds__(512, 1) void persist(
    const float* __restrict__ Wih0, const float* __restrict__ Whh0,
    const float* __restrict__ bih0, const float* __restrict__ bhh0,
    const float* __restrict__ Wih1, const float* __restrict__ Whh1,
    const float* __restrict__ bih1, const float* __restrict__ bhh1,
    const float* __restrict__ fcW,  const float* __restrict__ fcb,
    const float* __restrict__ x,    const short* __restrict__ xbf,
    short* __restrict__ h0A, short* __restrict__ hF,
    const short* __restrict__ Mf, const float* __restrict__ c0ws,
    float* __restrict__ outp,
    unsigned* __restrict__ flagA, unsigned* __restrict__ flagB)
{
    __shared__ f32x4 red[2048];     // 32 KB cross-wave reduce
    __shared__ short ldsC[16384];   // 32 KB fc weights (blocks nf<64)
    __shared__ unsigned tokA, tokB;
    const int tid = threadIdx.x, lane = tid & 63, w = tid >> 6;   // w 0..7
    const int nf = blockIdx.x;
    const int lane31 = lane & 31;
    unsigned* lineA = &flagA[(nf >> 3) * 16];
    unsigned* lineB = &flagB[(nf >> 3) * 16];
    const int rowp = nf * 16 + (lane & 15);
    const int up = rowp >> 2, g = rowp & 3;
    const int g1 = lane & 1, g2 = lane & 2;
    const f32x4 zero4 = {0, 0, 0, 0};
    // epilogue store constants (w<4)
    const int chunkA = (nf >> 3) * 4 + w;
    const int chunkL = (32 + (nf >> 3)) * 4 + w;
    const int lsBase = ((nf & 7) >> 1) * 16;
    const int pb = (nf & 1) * 4 + ((lane & 15) >> 3) * 2;
    const int mfc = nf >> 4;                       // fc m-tile (nf<64)

    if (tid == 0) { tokA = 0; tokB = 0; }

    // ---- prologue: weights -> registers ----
    bf16x8 wA[5];   // [0]=x (kf=w), [1..4]=h0 (kf0 = w*4+i-1)
    {
        int k = w * 32 + (lane >> 4) * 8;
        const float* src = Wih0 + (size_t)(g * H_ + up) * 512 + k;
        #pragma unroll
        for (int j = 0; j < 8; ++j) wA[0][j] = bfr(src[j]);
    }
    #pragma unroll
    for (int i = 1; i < 5; ++i) {
        int kh = (w * 4 + (i - 1)) * 32 + (lane >> 4) * 8;
        const float* src = Whh0 + (size_t)(g * H_ + up) * 1024 + kh;
        #pragma unroll
        for (int j = 0; j < 8; ++j) wA[i][j] = bfr(src[j]);
    }
    bf16x8 waQ;     // Wa (action cols of Wih0), kf=w
    {
        int k = 256 + w * 32 + (lane >> 4) * 8;
        const float* src = Wih0 + (size_t)(g * H_ + up) * 512 + k;
        #pragma unroll
        for (int j = 0; j < 8; ++j) waQ[j] = bfr(src[j]);
    }
    bf16x8 wB[8];
    #pragma unroll
    for (int i = 0; i < 8; ++i) {
        int kf = w * 8 + i;
        int k = kf * 32 + (lane >> 4) * 8;
        const float* src = (k < 1024) ? (Wih1 + (size_t)(g * H_ + up) * 1024 + k)
                                      : (Whh1 + (size_t)(g * H_ + up) * 1024 + (k - 1024));
        #pragma unroll
        for (int j = 0; j < 8; ++j) wB[i][j] = bfr(src[j]);
    }
    bf16x8 wM[4];
    #pragma unroll
    for (int i = 0; i < 4; ++i) {
        int kf = w * 4 + i;
        wM[i] = *(const bf16x8*)(Mf + ((size_t)nf * 32 + kf) * 512 + lane * 8);
    }
    const float bias0 = bih0[g * H_ + up] + bhh0[g * H_ + up];
    const float bias1 = bih1[g * H_ + up] + bhh1[g * H_ + up];
    const float c0l = c0ws[nf * 16 + (lane & 15)];
    float biasC = 0.0f;
    if (nf < 64) {
        int rowc = (nf & 15) * 16 + (lane & 15);
        biasC = fcb[rowc];
        #pragma unroll
        for (int i = 0; i < 4; ++i) {
            int kf = w * 4 + i;
            int k = kf * 32 + (lane >> 4) * 8;
            const float* src = fcW + (size_t)rowc * 1024 + k;
            short* d = ldsC + ((size_t)kf * 64 + lane) * 8;
            #pragma unroll
            for (int j = 0; j < 8; ++j) d[j] = bfr(src[j]);
        }
    }
    __syncthreads();

    float cs0[4] = {0, 0, 0, 0}, cs1[4] = {0, 0, 0, 0};
    float areg[4] = {0, 0, 0, 0}, P[4] = {0, 0, 0, 0};

    for (int t = 0; t < S_; ++t) {
        const int cur = t & 1, nxt = cur ^ 1;
        const short* h0Ac = h0A + cur * 65536;
        short* h0An = h0A + nxt * 65536;
        short* hFc = hF + cur * 131072;   // ih src (chunkA) + hh src h1(t-1) (chunkL)
        short* hFn = hF + nxt * 131072;   // h1(t) dst; read at D/E
        const unsigned ut = (unsigned)t;

        // ===== A1: x-MFMAs + Q-MFMAs (no guard; x frag shared) =====
        f32x4 ga0, ga1, ga2, ga3, q0, q1, q2, q3;
        {
            const short* p = xbf + (size_t)t * 16384 + (size_t)w * 2048 + lane * 8;
            bf16x8 a0 = *(const bf16x8*)(p);
            bf16x8 a1 = *(const bf16x8*)(p + 512);
            bf16x8 a2 = *(const bf16x8*)(p + 1024);
            bf16x8 a3 = *(const bf16x8*)(p + 1536);
            ga0 = MFMA(a0, wA[0], zero4);
            ga1 = MFMA(a1, wA[0], zero4);
            ga2 = MFMA(a2, wA[0], zero4);
            ga3 = MFMA(a3, wA[0], zero4);
            q0 = MFMA(a0, waQ, zero4);
            q1 = MFMA(a1, waQ, zero4);
            q2 = MFMA(a2, waQ, zero4);
            q3 = MFMA(a3, waQ, zero4);
        }
        // ===== A2: h0(t-1) frags (guard tokA>=t, already published at B1(t-1)) =====
        tok_spin(&tokA, ut);
        #pragma unroll
        for (int i = 1; i < 5; ++i) {
            const short* p = h0Ac + (size_t)(w * 4 + (i - 1)) * 2048 + lane * 8;
            bf16x8 a0 = lda16(p);
            bf16x8 a1 = lda16(p + 512);
            bf16x8 a2 = lda16(p + 1024);
            bf16x8 a3 = lda16(p + 1536);
            ga0 = MFMA(a0, wA[i], ga0);
            ga1 = MFMA(a1, wA[i], ga1);
            ga2 = MFMA(a2, wA[i], ga2);
            ga3 = MFMA(a3, wA[i], ga3);
        }
        // ===== A3: reduce + pointwise (P as extra bias) =====
        red[(w * 4 + 0) * 64 + lane] = ga0;
        red[(w * 4 + 1) * 64 + lane] = ga1;
        red[(w * 4 + 2) * 64 + lane] = ga2;
        red[(w * 4 + 3) * 64 + lane] = ga3;
        __syncthreads();
        if (w < 4) {
            f32x4 s = red[(0 * 4 + w) * 64 + lane];
            #pragma unroll
            for (int k = 1; k < 8; ++k) s += red[(k * 4 + w) * 64 + lane];
            #pragma unroll
            for (int r = 0; r < 4; ++r) {
                float v = s[r] + bias0 + P[r];
                GATES(v)
                float cn = f_ * cs0[r] + i_ * gc;
                cs0[r] = cn;
                float hn = o_ * tanh_(cn);
                int hv = (int)(unsigned short)bfr(hn);
                int ot = __shfl_xor(hv, 4);
                unsigned p32 = (lane & 4) ? (unsigned)((ot & 0xffff) | (hv << 16))
                                          : (unsigned)((hv & 0xffff) | (ot << 16));
                if ((lane & 7) == 0) {
                    int b = w * 16 + (lane >> 4) * 4 + r;
                    int ls = lsBase + (b & 15);
                    size_t off = (size_t)chunkA * 1024 + (size_t)ls * 16 + pb * 2;
                    st4(hFc, off, p32);    // layer1 ih operand
                    st4(h0An, off, p32);   // next-step layer0 operand
                }
            }
        }
        __syncthreads();
        if (tid == 0) flag_add(lineA);

        // ===== B1/B2: layer1. waves 0-3 (ih) wait flagA; waves 4-7 (hh) go now =====
        f32x4 b0 = zero4, b1 = zero4, b2 = zero4, b3 = zero4;
        if (w == 0) {
            flag_wait_g(flagA, lane31, 256u * (ut + 1u));
            if (lane == 0) *(volatile unsigned*)&tokA = ut + 1u;
            CBAR();
        } else if (w < 4) {
            tok_spin(&tokA, ut + 1u);
        }
        #pragma unroll
        for (int i = 0; i < 8; ++i) {
            const int kf = w * 8 + i;
            const short* p = hFc + (size_t)kf * 2048 + lane * 8;
            bf16x8 a0 = lda16(p);
            bf16x8 a1 = lda16(p + 512);
            bf16x8 a2 = lda16(p + 1024);
            bf16x8 a3 = lda16(p + 1536);
            b0 = MFMA(a0, wB[i], b0);
            b1 = MFMA(a1, wB[i], b1);
            b2 = MFMA(a2, wB[i], b2);
            b3 = MFMA(a3, wB[i], b3);
        }
        red[(w * 4 + 0) * 64 + lane] = b0;
        red[(w * 4 + 1) * 64 + lane] = b1;
        red[(w * 4 + 2) * 64 + lane] = b2;
        red[(w * 4 + 3) * 64 + lane] = b3;
        __syncthreads();
        if (w < 4) {
            f32x4 s = red[(0 * 4 + w) * 64 + lane];
            #pragma unroll
            for (int k = 1; k < 8; ++k) s += red[(k * 4 + w) * 64 + lane];
            #pragma unroll
            for (int r = 0; r < 4; ++r) {
                float v = s[r] + bias1;
                GATES(v)
                float cn = f_ * cs1[r] + i_ * gc;
                cs1[r] = cn;
                float hn = o_ * tanh_(cn);
                int hv = (int)(unsigned short)bfr(hn);
                int ot = __shfl_xor(hv, 4);
                unsigned p32 = (lane & 4) ? (unsigned)((ot & 0xffff) | (hv << 16))
                                          : (unsigned)((hv & 0xffff) | (ot << 16));
                if ((lane & 7) == 0) {
                    int b = w * 16 + (lane >> 4) * 4 + r;
                    int ls = lsBase + (b & 15);
                    st4(hFn, (size_t)chunkL * 1024 + (size_t)ls * 16 + pb * 2, p32);  // h1(t)
                }
            }
        }
        __syncthreads();
        if (tid == 0) flag_add(lineB);

        // ===== C: wait layer1 done chip-wide =====
        if (w == 0) {
            flag_wait_g(flagB, lane31, 256u * (ut + 1u));
            if (lane == 0) *(volatile unsigned*)&tokB = ut + 1u;
            CBAR();
        } else {
            tok_spin(&tokB, ut + 1u);
        }

        // ===== D: P-update  P = (1.15 Q + 0.15 P + 0.2 (M h1 + c0)) / 1.5 =====
        {
            f32x4 m0 = zero4, m1 = zero4, m2 = zero4, m3 = zero4;
            #pragma unroll
            for (int i = 0; i < 4; ++i) {
                const int kf = w * 4 + i;
                const short* p = hFn + (size_t)(32 + kf) * 2048 + lane * 8;
                bf16x8 a0 = lda16(p);
                bf16x8 a1 = lda16(p + 512);
                bf16x8 a2 = lda16(p + 1024);
                bf16x8 a3 = lda16(p + 1536);
                m0 = MFMA(a0, wM[i], m0);
                m1 = MFMA(a1, wM[i], m1);
                m2 = MFMA(a2, wM[i], m2);
                m3 = MFMA(a3, wM[i], m3);
            }
            f32x4 R0 = (t == 0) ? q0 : (1.15f * q0 + 0.2f * m0);
            f32x4 R1 = (t == 0) ? q1 : (1.15f * q1 + 0.2f * m1);
            f32x4 R2 = (t == 0) ? q2 : (1.15f * q2 + 0.2f * m2);
            f32x4 R3 = (t == 0) ? q3 : (1.15f * q3 + 0.2f * m3);
            red[(w * 4 + 0) * 64 + lane] = R0;
            red[(w * 4 + 1) * 64 + lane] = R1;
            red[(w * 4 + 2) * 64 + lane] = R2;
            red[(w * 4 + 3) * 64 + lane] = R3;
            __syncthreads();
            if (w < 4) {
                f32x4 s = red[(0 * 4 + w) * 64 + lane];
                #pragma unroll
                for (int k = 1; k < 8; ++k) s += red[(k * 4 + w) * 64 + lane];
                #pragma unroll
                for (int r = 0; r < 4; ++r)
                    P[r] = (t == 0) ? s[r]
                         : (s[r] + 0.15f * P[r] + 0.2f * c0l) * (1.0f / 1.5f);
            }
            __syncthreads();   // protect red before E / next A3
        }

        // ===== E: fc + blend + output (blocks nf<64; fully off the flag chain) =====
        if (nf < 64) {
            f32x4 f0 = zero4;
            #pragma unroll
            for (int i = 0; i < 4; ++i) {
                const int kf = w * 4 + i;
                const bf16x8 bw = *(const bf16x8*)(ldsC + ((size_t)kf * 64 + lane) * 8);
                const short* p = hFn + (size_t)(32 + kf) * 2048 + (size_t)mfc * 512 + lane * 8;
                f0 = MFMA(lda16(p), bw, f0);
            }
            red[w * 64 + lane] = f0;
            __syncthreads();
            if (w == 0) {
                f32x4 s = red[0 * 64 + lane];
                #pragma unroll
                for (int k = 1; k < 8; ++k) s += red[k * 64 + lane];
                const int c = (nf & 15) * 16 + (lane & 15);
                #pragma unroll
                for (int r = 0; r < 4; ++r) {
                    float ov = s[r] + biasC;
                    int b = mfc * 16 + (lane >> 4) * 4 + r;
                    size_t xi = ((size_t)b * S_ + t) * F_ + c;
                    float xv = x[xi];
                    float na = (t == 0) ? xv
                             : (1.15f * xv + 0.15f * areg[r] + 0.2f * ov) * (1.0f / 1.5f);
                    areg[r] = na;
                    outp[xi] = na;
                }
            }
            __syncthreads();   // protect red before next A3
        }
    }
}

extern "C" void kernel_launch(void* const* d_in, const int* in_sizes, int n_in,
                              void* d_out, int out_size, void* d_ws, size_t ws_size,
                              hipStream_t stream) {
    const float* x    = (const float*)d_in[0];
    const float* Wih0 = (const float*)d_in[1];
    const float* Whh0 = (const float*)d_in[2];
    const float* bih0 = (const float*)d_in[3];
    const float* bhh0 = (const float*)d_in[4];
    const float* Wih1 = (const float*)d_in[5];
    const float* Whh1 = (const float*)d_in[6];
    const float* bih1 = (const float*)d_in[7];
    const float* bhh1 = (const float*)d_in[8];
    const float* fcW  = (const float*)d_in[9];
    const float* fcb  = (const float*)d_in[10];
    float* outp = (float*)d_out;

    char* ws = (char*)d_ws;
    short* xbf   = (short*)(ws + 0);                // 8,388,608 B
    short* h0A   = (short*)(ws + 8388608);          //   262,144 B (2 x 65536 sh)
    short* hF    = (short*)(ws + 8650752);          //   524,288 B (2 x 131072 sh)
    short* Mf    = (short*)(ws + 9175040);          // 8,388,608 B (M B-frags)
    float* c0ws  = (float*)(ws + 17563648);         //    16,384 B (4096 f32)
    unsigned* flagA = (unsigned*)(ws + 17580032);   //     2,048 B (32 lines)
    unsigned* flagB = (unsigned*)(ws + 17582080);   //     2,048 B (32 lines)

    conv_x<<<2048, 256, 0, stream>>>(x, xbf);
    precomp<<<256, 256, 0, stream>>>(Wih0, fcW, fcb, Mf, c0ws);
    zero_f<<<768, 256, 0, stream>>>((float*)(ws + 8388608), 196608);   // h0A + hF
    zero_f<<<4, 256, 0, stream>>>((float*)(ws + 17580032), 1024);      // flags

    persist<<<256, 512, 0, stream>>>(Wih0, Whh0, bih0, bhh0,
                                     Wih1, Whh1, bih1, bhh1,
                                     fcW, fcb, x, xbf,
                                     h0A, hF, Mf, c0ws, outp,
                                     flagA, flagB);
}